// Round 13
// baseline (375.111 us; speedup 1.0000x reference)
//
#include <hip/hip_runtime.h>
#include <math.h>

// Problem constants
#define BB 4
#define CH 32
#define HH 96
#define WW 96
#define LL (HH*WW)          // 9216 tokens per image
#define DI 64               // inner dim
#define NS 16               // state dim
#define BL (BB*LL)          // 36864 total tokens
#define NCH 576             // scan chunks per sequence
#define CLEN (LL/NCH)       // 16 steps per chunk
#define GG 4                // token group size in k3 (fence amortization)

__device__ __forceinline__ float sigmoidf_(float x){ return 1.f/(1.f+__expf(-x)); }
__device__ __forceinline__ float siluf_(float x){ return x*sigmoidf_(x); }
__device__ __forceinline__ float softplusf_(float x){
  return (x > 15.f) ? x : __logf(1.f + __expf(x));
}
// single-wave LDS fence: order ds_write -> ds_read within one wave without
// s_barrier (avoids the vmcnt(0) drain __syncthreads would impose)
#define WAVE_LDS_FENCE() do { asm volatile("s_waitcnt lgkmcnt(0)" ::: "memory"); __builtin_amdgcn_sched_barrier(0); } while(0)

// ---------------------------------------------------------------- K1: dilated depthwise 7x7 conv (pad=9, dil=3)
__global__ __launch_bounds__(256) void k1_conv_att(
    const float* __restrict__ x, const float* __restrict__ w,
    const float* __restrict__ bias, float* __restrict__ xa){
  int idx = blockIdx.x*256 + threadIdx.x;
  if (idx >= BB*CH*LL) return;
  int w0 = idx % WW; int h0 = (idx/WW) % HH; int c = (idx/LL) % CH;
  const float* xp = x + (idx/LL)*LL;   // (b,c) plane
  const float* wp = w + c*49;
  float acc = bias[c];
  #pragma unroll
  for (int kh=0; kh<7; ++kh){
    int hh = h0 + 3*kh - 9;
    if ((unsigned)hh >= HH) continue;
    const float* row = xp + hh*WW;
    #pragma unroll
    for (int kw=0; kw<7; ++kw){
      int ww = w0 + 3*kw - 9;
      if ((unsigned)ww < WW) acc += row[ww]*wp[kh*7+kw];
    }
  }
  xa[idx] = acc;   // (B,C,L)
}

// ---------------------------------------------------------------- K2: LayerNorm + in_proj + split + silu(z)
__global__ __launch_bounds__(128) void k2_ln_inproj(
    const float* __restrict__ xa, const float* __restrict__ w_in,
    const float* __restrict__ ln_w, const float* __restrict__ ln_b,
    float* __restrict__ xin, float* __restrict__ zs){
  __shared__ float xs[CH*36];      // [c][tok], stride 36 keeps float4 alignment
  __shared__ float smu[32], srs[32];
  int tid = threadIdx.x;
  int tg0 = blockIdx.x*32;
  int bb = tg0 / LL;
  int l0 = tg0 % LL;
  const float* xab = xa + bb*CH*LL + l0;
  for (int r=0; r<8; ++r){
    int idx = r*128 + tid;          // 1024 = 32c x 32t
    int c = idx >> 5, t = idx & 31;
    xs[c*36+t] = xab[c*LL + t];
  }
  int j = tid;
  float wlj[CH];
  float swl=0.f, bj=0.f;
  #pragma unroll
  for (int c=0;c<CH;++c){
    float wv = ln_w[c]*w_in[j*CH+c];
    wlj[c] = wv; swl += wv;
    bj += ln_b[c]*w_in[j*CH+c];
  }
  __syncthreads();
  if (tid < 32){
    float s=0.f, s2=0.f;
    #pragma unroll
    for (int c=0;c<CH;++c){ float v = xs[c*36+tid]; s+=v; s2+=v*v; }
    float mu = s*(1.f/CH);
    float var = s2*(1.f/CH) - mu*mu;
    smu[tid]=mu; srs[tid]=rsqrtf(var+1e-5f);
  }
  __syncthreads();
  for (int t4=0;t4<8;++t4){
    float a0=0.f,a1=0.f,a2=0.f,a3=0.f;
    #pragma unroll
    for (int c=0;c<CH;++c){
      float4 xv = *(const float4*)&xs[c*36 + t4*4];   // wave-uniform broadcast
      float wv = wlj[c];
      a0 += xv.x*wv; a1 += xv.y*wv; a2 += xv.z*wv; a3 += xv.w*wv;
    }
    float av[4] = {a0,a1,a2,a3};
    #pragma unroll
    for (int q=0;q<4;++q){
      int t = t4*4+q;
      float out = srs[t]*(av[q] - smu[t]*swl) + bj;
      int base = ((bb*LL) + l0 + t)*DI;
      if (j < DI) xin[base + j] = out;
      else        zs[base + (j-DI)] = siluf_(out);
    }
  }
}

// ---------------------------------------------------------------- K3 fused v5: conv1d+silu + x_proj + softplus + local scan
// Register-lean: wreg[32] (row split across lane pairs, shfl_xor combine),
// dt via 64-lane butterfly (no dtb LDS), no prefetch. CLEN=16, GG=4.
// Emits y_local, sdl-prefix, Cc, chunk aggregates.
__global__ __launch_bounds__(64) void k3_fused(
    const float* __restrict__ xin,
    const float* __restrict__ cw_f, const float* __restrict__ cb_f,
    const float* __restrict__ wx_f, const float* __restrict__ wdt_f, const float* __restrict__ bdt_f,
    const float* __restrict__ Al_f, const float* __restrict__ D_f,
    const float* __restrict__ cw_b, const float* __restrict__ cb_b,
    const float* __restrict__ wx_b, const float* __restrict__ wdt_b, const float* __restrict__ bdt_b,
    const float* __restrict__ Al_b, const float* __restrict__ D_b,
    float* __restrict__ yl_f, float* __restrict__ sp_f, float* __restrict__ Cc_f,
    float* __restrict__ yl_b, float* __restrict__ sp_b, float* __restrict__ Cc_b,
    float* __restrict__ aggP, float* __restrict__ aggS){
  int lane = threadIdx.x;
  int dir = blockIdx.y;
  int bb = blockIdx.z;
  int ch = blockIdx.x;
  int p0 = ch*CLEN;
  const float* cw  = dir? cw_b : cw_f;
  const float* cb  = dir? cb_b : cb_f;
  const float* wx  = dir? wx_b : wx_f;
  const float* wdt = dir? wdt_b : wdt_f;
  const float* bdt = dir? bdt_b : bdt_f;
  const float* Al  = dir? Al_b : Al_f;
  const float* Dv  = dir? D_b : D_f;
  float* ylbuf = dir? yl_b : yl_f;
  float* spbuf = dir? sp_b : sp_f;
  float* Ccb   = dir? Cc_b : Cc_f;

  __shared__ float xcs[GG*64];   // group of xc rows
  __shared__ float bcs[GG*16];   // group of Bc rows
  __shared__ float ccs[GG*16];   // group of Cc rows

  // ---- per-lane constants
  int d = lane;
  float c0=cw[d*4+0], c1=cw[d*4+1], c2=cw[d*4+2], c3=cw[d*4+3], cbv=cb[d];
  float wd0=wdt[d*2], wd1=wdt[d*2+1], bd=bdt[d];
  float Dd = Dv[d];
  float A[NS];
  #pragma unroll
  for (int n4=0;n4<4;++n4){
    float4 av = *(const float4*)&Al[d*NS + n4*4];
    A[n4*4+0] = -__expf(av.x); A[n4*4+1] = -__expf(av.y);
    A[n4*4+2] = -__expf(av.z); A[n4*4+3] = -__expf(av.w);
  }
  // x_proj: lane l owns row 2+(l&31), c-half (l>>5) -> 32 weights in regs
  int prow = 2 + (lane & 31);
  int chalf = lane >> 5;
  float wreg[32];
  #pragma unroll
  for (int i4=0;i4<8;++i4){
    float4 wv = *(const float4*)&wx[prow*64 + chalf*32 + i4*4];
    wreg[i4*4+0]=wv.x; wreg[i4*4+1]=wv.y; wreg[i4*4+2]=wv.z; wreg[i4*4+3]=wv.w;
  }
  // dt rows 0,1: lane d holds wx[0][d], wx[1][d]
  float wx0l = wx[d], wx1l = wx[64+d];
  // scan state: S (local state) + sdl (running sum of deltas)
  float S[NS];
  #pragma unroll
  for (int n=0;n<NS;++n) S[n]=0.f;
  float sdl = 0.f;
  // conv history
  float u1=0.f,u2=0.f,u3=0.f;
  #pragma unroll
  for (int k=1;k<=3;++k){
    int pos = p0 - k;
    float v = 0.f;
    if (pos >= 0){ int ls = dir? (LL-1-pos) : pos; v = xin[(bb*LL+ls)*DI + d]; }
    if(k==1) u1=v; else if(k==2) u2=v; else u3=v;
  }

  const int NG = CLEN/GG;   // 4
  for (int g=0; g<NG; ++g){
    int pbase = p0 + g*GG;
    // ---- phase A: conv1d + silu + dt-butterfly for GG tokens
    float xcr[GG], dlt[GG];
    #pragma unroll
    for (int j=0;j<GG;++j){
      int pos = pbase + j;
      int ls = dir? (LL-1-pos) : pos;
      float u0 = xin[(bb*LL+ls)*DI + d];
      float xc = siluf_(cbv + c0*u3 + c1*u2 + c2*u1 + c3*u0);
      u3=u2; u2=u1; u1=u0;
      xcr[j] = xc;
      xcs[j*64+d] = xc;
      // dt0/dt1 wave reduction (all 64 lanes)
      float pp0 = xc*wx0l, pp1 = xc*wx1l;
      #pragma unroll
      for (int i=1;i<64;i<<=1){
        pp0 += __shfl_xor(pp0, i, 64);
        pp1 += __shfl_xor(pp1, i, 64);
      }
      dlt[j] = softplusf_(pp0*wd0 + pp1*wd1 + bd);
    }
    WAVE_LDS_FENCE();
    // ---- phase B: x_proj rows 2..33, split across lane pairs
    #pragma unroll
    for (int j=0;j<GG;++j){
      float acc = 0.f;
      #pragma unroll
      for (int c4=0;c4<8;++c4){
        float4 xv = *(const float4*)&xcs[j*64 + chalf*32 + c4*4];
        acc += xv.x*wreg[c4*4+0] + xv.y*wreg[c4*4+1]
             + xv.z*wreg[c4*4+2] + xv.w*wreg[c4*4+3];
      }
      float full = acc + __shfl_xor(acc, 32, 64);
      if (lane < 32){
        if (lane < 16){
          bcs[j*16 + lane] = full;                 // Bc (LDS only)
        } else {
          int n = lane - 16;
          ccs[j*16 + n] = full;                    // Cc (LDS + global for k4)
          Ccb[(bb*LL + pbase + j)*NS + n] = full;
        }
      }
    }
    WAVE_LDS_FENCE();
    // ---- phase C: scan + y_local/sdl-prefix writes (lane = d)
    #pragma unroll
    for (int j=0;j<GG;++j){
      int tb = bb*LL + pbase + j;
      float dl = dlt[j];
      sdl += dl;                              // inclusive prefix
      spbuf[tb*DI + d] = sdl;
      float dx = dl*xcr[j];
      float yv = xcr[j]*Dd;
      #pragma unroll
      for (int n4=0;n4<4;++n4){
        float4 bv = *(const float4*)&bcs[j*16 + n4*4];   // broadcast
        float4 cv = *(const float4*)&ccs[j*16 + n4*4];   // broadcast
        float bvv[4] = {bv.x,bv.y,bv.z,bv.w};
        float cvv[4] = {cv.x,cv.y,cv.z,cv.w};
        #pragma unroll
        for (int q=0;q<4;++q){
          int n = n4*4+q;
          float dA = __expf(dl*A[n]);
          S[n] = dA*S[n] + dx*bvv[q];
          yv += S[n]*cvv[q];
        }
      }
      ylbuf[tb*DI + d] = yv;
    }
  }
  // write chunk aggregates; P[n] = exp(A[n]*sdl)
  int bdd = (bb*2+dir)*DI + d;
  float* pp = aggP + (bdd*NCH + ch)*NS;
  float* sp = aggS + (bdd*NCH + ch)*NS;
  #pragma unroll
  for (int n4=0;n4<4;++n4){
    *(float4*)&pp[n4*4] = make_float4(__expf(A[n4*4+0]*sdl),__expf(A[n4*4+1]*sdl),
                                      __expf(A[n4*4+2]*sdl),__expf(A[n4*4+3]*sdl));
    *(float4*)&sp[n4*4] = make_float4(S[n4*4+0],S[n4*4+1],S[n4*4+2],S[n4*4+3]);
  }
}

// ---------------------------------------------------------------- P2: scan over chunk aggregates -> incoming state per chunk
// NOTE: hin aliases aggP (in-place); read-before-write per element.
__global__ __launch_bounds__(256) void p2_scan_agg(
    const float* aggP, const float* aggS, float* hin){
  int t = blockIdx.x*256 + threadIdx.x; // 8192 chains
  if (t >= BB*2*DI*NS) return;
  int bdd = t >> 4, n = t & 15;
  float h = 0.f;
  #pragma unroll 4
  for (int k=0;k<NCH;++k){
    int i = (bdd*NCH + k)*NS + n;
    float pv = aggP[i], sv = aggS[i];
    hin[i] = h;
    h = pv*h + sv;
  }
}

// ---------------------------------------------------------------- K4: hin-correction + gate + out_proj + transpose -> att2
// y[t,d] = yl[t,d] + sum_n Cc[t,n]*exp(A[d,n]*sp[t,d])*hin[ch,d,n]  (both dirs)
// tile = 32 tokens = 2 chunks per dir (CLEN=16); chunk fixed per tslot.
__global__ __launch_bounds__(256) void k4_outproj(
    const float* __restrict__ yl_f, const float* __restrict__ yl_b,
    const float* __restrict__ sp_f, const float* __restrict__ sp_b,
    const float* __restrict__ Cc_f, const float* __restrict__ Cc_b,
    const float* __restrict__ Al_f, const float* __restrict__ Al_b,
    const float* __restrict__ hin, const float* __restrict__ zs,
    const float* __restrict__ w_out, float* __restrict__ att2){
  __shared__ float ccs_f[32*16], ccs_b[32*16];
  __shared__ float gt[32*64];    // [tok][d]
  __shared__ float wol[32*65];   // [c][d] padded
  __shared__ float ot[32*33];    // [c][tok] padded
  int tid = threadIdx.x;
  int tg0 = blockIdx.x*32;
  int bb = tg0/LL, l0 = tg0%LL;
  int d = tid & 63, tslot = tid >> 6;
  for (int r=0;r<8;++r){
    int idx = r*256+tid; // 2048
    wol[(idx>>6)*65 + (idx&63)] = w_out[idx];
  }
  {
    int base_f = (bb*LL + l0)*NS;
    int base_b = (bb*LL + (LL-32-l0))*NS;
    #pragma unroll
    for (int r=0;r<2;++r){
      int idx = r*256+tid;  // 512
      ccs_f[idx] = Cc_f[base_f+idx];
      ccs_b[idx] = Cc_b[base_b+idx];
    }
  }
  // per-thread A and hin; chunk is fixed per tslot (CLEN=16, 8 tokens/tslot)
  int ch_f = l0/CLEN + (tslot>>1);
  int ch_b = (LL-l0)/CLEN - 1 - (tslot>>1);
  const float* hpf = hin + (((bb*2+0)*DI + d)*NCH + ch_f)*NS;
  const float* hpb = hin + (((bb*2+1)*DI + d)*NCH + ch_b)*NS;
  float Af[NS], Ab[NS], hf[NS], hb[NS];
  #pragma unroll
  for (int n4=0;n4<4;++n4){
    float4 av = *(const float4*)&Al_f[d*NS + n4*4];
    Af[n4*4+0]=-__expf(av.x); Af[n4*4+1]=-__expf(av.y);
    Af[n4*4+2]=-__expf(av.z); Af[n4*4+3]=-__expf(av.w);
    float4 aw = *(const float4*)&Al_b[d*NS + n4*4];
    Ab[n4*4+0]=-__expf(aw.x); Ab[n4*4+1]=-__expf(aw.y);
    Ab[n4*4+2]=-__expf(aw.z); Ab[n4*4+3]=-__expf(aw.w);
    float4 hv = *(const float4*)&hpf[n4*4];
    hf[n4*4+0]=hv.x; hf[n4*4+1]=hv.y; hf[n4*4+2]=hv.z; hf[n4*4+3]=hv.w;
    float4 hw = *(const float4*)&hpb[n4*4];
    hb[n4*4+0]=hw.x; hb[n4*4+1]=hw.y; hb[n4*4+2]=hw.z; hb[n4*4+3]=hw.w;
  }
  __syncthreads();
  #pragma unroll
  for (int r=0;r<8;++r){
    int tk = tslot*8 + r;            // wave-uniform
    int l = l0 + tk;
    int tf  = (bb*LL + l)*DI + d;
    int tb2 = (bb*LL + (LL-1-l))*DI + d;
    float spf = sp_f[tf],  yf = yl_f[tf];
    float spb = sp_b[tb2], yb = yl_b[tb2];
    int jb = 31 - tk;
    float fixf = 0.f, fixb = 0.f;
    #pragma unroll
    for (int n=0;n<NS;++n){
      fixf += ccs_f[tk*16+n] * (hf[n]*__expf(Af[n]*spf));
      fixb += ccs_b[jb*16+n] * (hb[n]*__expf(Ab[n]*spb));
    }
    gt[tk*64+d] = (yf+fixf + yb+fixb) * zs[tf];
  }
  __syncthreads();
  int c = tid & 31, tsl = tid >> 5;
  for (int tg=0; tg<4; ++tg){
    int tk = tg*8+tsl;
    float acc=0.f;
    #pragma unroll
    for (int dd=0;dd<DI;++dd) acc += gt[tk*64+dd]*wol[c*65+dd];
    ot[c*33+tk] = acc;
  }
  __syncthreads();
  float* a2 = att2 + bb*CH*LL + l0;
  for (int r=0;r<4;++r){
    int idx = r*256+tid;   // 1024 = 32c x 32t
    int cc2 = idx>>5, t = idx&31;
    a2[cc2*LL + t] = ot[cc2*33+t];
  }
}

// ---------------------------------------------------------------- K5a: channel mean/max pool; 4-way c-split + LDS combine
__global__ __launch_bounds__(256) void k5a_pool(
    const float* __restrict__ x, const float* __restrict__ att2, float* __restrict__ pooled){
  __shared__ float ps[4][64], pm[4][64];
  int tid = threadIdx.x;
  int lq = tid & 63, q = tid >> 6;
  int gl = blockIdx.x*64 + lq;
  int bb = gl/LL, l = gl%LL;
  const float* xp = x + bb*CH*LL + l;
  const float* ap = att2 + bb*CH*LL + l;
  float s=0.f, m=-INFINITY;
  #pragma unroll
  for (int cc=0;cc<8;++cc){
    int c = q*8+cc;
    float v1 = xp[c*LL], v2 = ap[c*LL];
    s += v1+v2;
    m = fmaxf(m, fmaxf(v1,v2));
  }
  ps[q][lq] = s; pm[q][lq] = m;
  __syncthreads();
  if (tid < 64){
    int gl2 = blockIdx.x*64 + tid;
    int bb2 = gl2/LL, l2 = gl2%LL;
    float ss = (ps[0][tid]+ps[1][tid]) + (ps[2][tid]+ps[3][tid]);
    float mm = fmaxf(fmaxf(pm[0][tid],pm[1][tid]), fmaxf(pm[2][tid],pm[3][tid]));
    pooled[(bb2*2+0)*LL + l2] = ss*(1.f/64.f);
    pooled[(bb2*2+1)*LL + l2] = mm;
  }
}

// ---------------------------------------------------------------- K5b: 7x7 SE conv + sigmoid + combine; 4-way (o,i)-split
__global__ __launch_bounds__(256) void k5b_se_combine(
    const float* __restrict__ x, const float* __restrict__ att2,
    const float* __restrict__ pooled, const float* __restrict__ w_se,
    const float* __restrict__ b_se, float* __restrict__ outbuf){
  __shared__ float pb[4][64];
  __shared__ float sep[2][64];
  int tid = threadIdx.x;
  int lq = tid & 63, q = tid >> 6;
  int i = q & 1, o = q >> 1;
  int gl = blockIdx.x*64 + lq;
  int bb = gl/LL, l = gl%LL;
  int h0 = l/WW, w0 = l%WW;
  const float* pp = pooled + (bb*2+i)*LL;
  const float* wp = w_se + (o*2+i)*49;
  float a = 0.f;
  #pragma unroll
  for (int kh=0;kh<7;++kh){
    int hh = h0+kh-3; if((unsigned)hh>=HH) continue;
    const float* row = pp + hh*WW;
    #pragma unroll
    for (int kw=0;kw<7;++kw){
      int ww2 = w0+kw-3;
      if((unsigned)ww2<WW) a += row[ww2]*wp[kh*7+kw];
    }
  }
  pb[q][lq] = a;
  __syncthreads();
  if (tid < 128){
    int oo = tid >> 6, l2 = tid & 63;
    sep[oo][l2] = sigmoidf_(b_se[oo] + pb[oo*2+0][l2] + pb[oo*2+1][l2]);
  }
  __syncthreads();
  float se0 = sep[0][lq], se1 = sep[1][lq];
  const float* xp = x + bb*CH*LL + l;
  const float* ap = att2 + bb*CH*LL + l;
  float* op = outbuf + bb*CH*LL + l;
  #pragma unroll
  for (int cc=0;cc<8;++cc){
    int c = q*8+cc;
    op[c*LL] = xp[c*LL]*se0 + ap[c*LL]*se1;
  }
}

// ---------------------------------------------------------------- K6: 3x3 conv 32->64 (pad=1), LDS row-banded, co-split
__global__ __launch_bounds__(256) void k6_conv3x3(
    const float* __restrict__ inb, const float* __restrict__ wc,
    const float* __restrict__ bc, float* __restrict__ out){
  __shared__ float lds[CH*3*98];
  int tid = threadIdx.x;
  int h = blockIdx.x, cohalf = blockIdx.y, bb = blockIdx.z;
  const float* ib = inb + bb*CH*LL;
  for (int r=0; r<36; ++r){           // 36*256 = 9216 = 32ci*3rows*96w
    int idx = r*256+tid;
    int ci = idx/(3*96); int rr = (idx/96)%3; int ww2 = idx%96;
    int hh = h + rr - 1;
    float v = ((unsigned)hh < HH) ? ib[ci*LL + hh*WW + ww2] : 0.f;
    lds[(ci*3+rr)*98 + 1 + ww2] = v;
  }
  if (tid < 96){
    int ci = tid/3, rr = tid%3;
    lds[(ci*3+rr)*98 + 0]  = 0.f;
    lds[(ci*3+rr)*98 + 97] = 0.f;
  }
  __syncthreads();
  int coslot = tid >> 4, wslot = tid & 15;
  int co0 = cohalf*32 + coslot*2, wb = wslot*6;
  float acc[2][6];
  #pragma unroll
  for (int q=0;q<2;++q)
    #pragma unroll
    for (int j2=0;j2<6;++j2) acc[q][j2]=0.f;
  for (int ci=0; ci<CH; ++ci){
    float wt[2][9];
    #pragma unroll
    for (int q=0;q<2;++q){
      const float* wp = wc + ((co0+q)*CH + ci)*9;
      #pragma unroll
      for (int k=0;k<9;++k) wt[q][k] = wp[k];
    }
    #pragma unroll
    for (int kh=0;kh<3;++kh){
      const float* row = &lds[(ci*3+kh)*98 + wb];
      float s[8];
      #pragma unroll
      for (int t2=0;t2<8;++t2) s[t2] = row[t2];
      #pragma unroll
      for (int q=0;q<2;++q)
        #pragma unroll
        for (int kw=0;kw<3;++kw){
          float wv = wt[q][kh*3+kw];
          #pragma unroll
          for (int j2=0;j2<6;++j2) acc[q][j2] += s[j2+kw]*wv;
        }
    }
  }
  #pragma unroll
  for (int q=0;q<2;++q){
    int co = co0+q;
    float bv = bc[co];
    float* op = out + (bb*64 + co)*LL + h*WW + wb;
    #pragma unroll
    for (int j2=0;j2<6;++j2) op[j2] = acc[q][j2]+bv;
  }
}

// ---------------------------------------------------------------- launch
extern "C" void kernel_launch(void* const* d_in, const int* in_sizes, int n_in,
                              void* d_out, int out_size, void* d_ws, size_t ws_size,
                              hipStream_t stream){
  const float* x     = (const float*)d_in[0];
  const float* w_att = (const float*)d_in[1];
  const float* b_att = (const float*)d_in[2];
  const float* ln_w  = (const float*)d_in[3];
  const float* ln_b  = (const float*)d_in[4];
  const float* w_in  = (const float*)d_in[5];
  const float* cw_f  = (const float*)d_in[6];
  const float* cb_f  = (const float*)d_in[7];
  const float* wx_f  = (const float*)d_in[8];
  const float* wdt_f = (const float*)d_in[9];
  const float* bdt_f = (const float*)d_in[10];
  const float* Al_f  = (const float*)d_in[11];
  const float* D_f   = (const float*)d_in[12];
  const float* cw_b  = (const float*)d_in[13];
  const float* cb_b  = (const float*)d_in[14];
  const float* wx_b  = (const float*)d_in[15];
  const float* wdt_b = (const float*)d_in[16];
  const float* bdt_b = (const float*)d_in[17];
  const float* Al_b  = (const float*)d_in[18];
  const float* D_b   = (const float*)d_in[19];
  const float* w_out = (const float*)d_in[20];
  const float* w_se  = (const float*)d_in[21];
  const float* b_se  = (const float*)d_in[22];
  const float* w_conv= (const float*)d_in[23];
  const float* b_conv= (const float*)d_in[24];

  float* ws = (float*)d_ws;
  // region aliasing (stream-ordered):
  //   xa (dead after K2)  <- att2 (written K4)
  //   xin (dead after K3) <- outbuf (written K5b)
  //   hin = aggP in-place (P2 reads agg[i] before writing hin[i])
  float* xa     = ws + 0;          // 1179648
  float* att2   = ws + 0;
  float* xin    = ws + 1179648;    // 2359296
  float* outbuf = ws + 1179648;
  float* zs     = ws + 3538944;    // 2359296
  float* yl_f   = ws + 5898240;    // 2359296
  float* yl_b   = ws + 8257536;    // 2359296
  float* sp_f   = ws + 10616832;   // 2359296
  float* sp_b   = ws + 12976128;   // 2359296
  float* Cc_f   = ws + 15335424;   // 589824
  float* Cc_b   = ws + 15925248;   // 589824
  float* aggP   = ws + 16515072;   // 4718592 (NCH=576)
  float* aggS   = ws + 21233664;   // 4718592
  float* hin    = aggP;            // in-place
  float* pooled = ws + 25952256;   // 73728
  // total 26025984 floats = 99.3 MiB

  k1_conv_att<<<4608,256,0,stream>>>(x, w_att, b_att, xa);
  k2_ln_inproj<<<1152,128,0,stream>>>(xa, w_in, ln_w, ln_b, xin, zs);
  k3_fused<<<dim3(NCH,2,BB),64,0,stream>>>(xin,
      cw_f,cb_f,wx_f,wdt_f,bdt_f,Al_f,D_f,
      cw_b,cb_b,wx_b,wdt_b,bdt_b,Al_b,D_b,
      yl_f,sp_f,Cc_f, yl_b,sp_b,Cc_b, aggP,aggS);
  p2_scan_agg<<<32,256,0,stream>>>(aggP,aggS,hin);
  k4_outproj<<<1152,256,0,stream>>>(yl_f,yl_b, sp_f,sp_b, Cc_f,Cc_b,
      Al_f,Al_b, hin, zs, w_out, att2);
  k5a_pool<<<576,256,0,stream>>>(x, att2, pooled);
  k5b_se_combine<<<576,256,0,stream>>>(x, att2, pooled, w_se, b_se, outbuf);
  k6_conv3x3<<<dim3(HH,2,BB),256,0,stream>>>(outbuf, w_conv, b_conv, (float*)d_out);
}

// Round 15
// 298.583 us; speedup vs baseline: 1.2563x; 1.2563x over previous
//
#include <hip/hip_runtime.h>
#include <math.h>

// Problem constants
#define BB 4
#define CH 32
#define HH 96
#define WW 96
#define LL (HH*WW)          // 9216 tokens per image
#define DI 64               // inner dim
#define NS 16               // state dim
#define BL (BB*LL)          // 36864 total tokens
#define NCH 576             // scan chunks per sequence
#define CLEN (LL/NCH)       // 16 steps per chunk
#define GG 4                // token group size in k3 (fence amortization)

__device__ __forceinline__ float sigmoidf_(float x){ return 1.f/(1.f+__expf(-x)); }
__device__ __forceinline__ float siluf_(float x){ return x*sigmoidf_(x); }
__device__ __forceinline__ float softplusf_(float x){
  return (x > 15.f) ? x : __logf(1.f + __expf(x));
}
// single-wave LDS fence: order ds_write -> ds_read within one wave without
// s_barrier (avoids the vmcnt(0) drain __syncthreads would impose)
#define WAVE_LDS_FENCE() do { asm volatile("s_waitcnt lgkmcnt(0)" ::: "memory"); __builtin_amdgcn_sched_barrier(0); } while(0)

// ---------------------------------------------------------------- K1: dilated depthwise 7x7 conv (pad=9, dil=3)
__global__ __launch_bounds__(256) void k1_conv_att(
    const float* __restrict__ x, const float* __restrict__ w,
    const float* __restrict__ bias, float* __restrict__ xa){
  int idx = blockIdx.x*256 + threadIdx.x;
  if (idx >= BB*CH*LL) return;
  int w0 = idx % WW; int h0 = (idx/WW) % HH; int c = (idx/LL) % CH;
  const float* xp = x + (idx/LL)*LL;   // (b,c) plane
  const float* wp = w + c*49;
  float acc = bias[c];
  #pragma unroll
  for (int kh=0; kh<7; ++kh){
    int hh = h0 + 3*kh - 9;
    if ((unsigned)hh >= HH) continue;
    const float* row = xp + hh*WW;
    #pragma unroll
    for (int kw=0; kw<7; ++kw){
      int ww = w0 + 3*kw - 9;
      if ((unsigned)ww < WW) acc += row[ww]*wp[kh*7+kw];
    }
  }
  xa[idx] = acc;   // (B,C,L)
}

// ---------------------------------------------------------------- K2: LayerNorm + in_proj + split + silu(z)
__global__ __launch_bounds__(128) void k2_ln_inproj(
    const float* __restrict__ xa, const float* __restrict__ w_in,
    const float* __restrict__ ln_w, const float* __restrict__ ln_b,
    float* __restrict__ xin, float* __restrict__ zs){
  __shared__ float xs[CH*36];      // [c][tok], stride 36 keeps float4 alignment
  __shared__ float smu[32], srs[32];
  int tid = threadIdx.x;
  int tg0 = blockIdx.x*32;
  int bb = tg0 / LL;
  int l0 = tg0 % LL;
  const float* xab = xa + bb*CH*LL + l0;
  for (int r=0; r<8; ++r){
    int idx = r*128 + tid;          // 1024 = 32c x 32t
    int c = idx >> 5, t = idx & 31;
    xs[c*36+t] = xab[c*LL + t];
  }
  int j = tid;
  float wlj[CH];
  float swl=0.f, bj=0.f;
  #pragma unroll
  for (int c=0;c<CH;++c){
    float wv = ln_w[c]*w_in[j*CH+c];
    wlj[c] = wv; swl += wv;
    bj += ln_b[c]*w_in[j*CH+c];
  }
  __syncthreads();
  if (tid < 32){
    float s=0.f, s2=0.f;
    #pragma unroll
    for (int c=0;c<CH;++c){ float v = xs[c*36+tid]; s+=v; s2+=v*v; }
    float mu = s*(1.f/CH);
    float var = s2*(1.f/CH) - mu*mu;
    smu[tid]=mu; srs[tid]=rsqrtf(var+1e-5f);
  }
  __syncthreads();
  for (int t4=0;t4<8;++t4){
    float a0=0.f,a1=0.f,a2=0.f,a3=0.f;
    #pragma unroll
    for (int c=0;c<CH;++c){
      float4 xv = *(const float4*)&xs[c*36 + t4*4];   // wave-uniform broadcast
      float wv = wlj[c];
      a0 += xv.x*wv; a1 += xv.y*wv; a2 += xv.z*wv; a3 += xv.w*wv;
    }
    float av[4] = {a0,a1,a2,a3};
    #pragma unroll
    for (int q=0;q<4;++q){
      int t = t4*4+q;
      float out = srs[t]*(av[q] - smu[t]*swl) + bj;
      int base = ((bb*LL) + l0 + t)*DI;
      if (j < DI) xin[base + j] = out;
      else        zs[base + (j-DI)] = siluf_(out);
    }
  }
}

// ---------------------------------------------------------------- K3 fused v5: conv1d+silu + x_proj + softplus + local scan
// Register-lean: wreg[32] (row split across lane pairs, shfl_xor combine),
// dt via 64-lane butterfly (no dtb LDS). CLEN=16, GG=4.
// Emits y_local, sdl-prefix, Cc, chunk aggregates.
__global__ __launch_bounds__(64) void k3_fused(
    const float* __restrict__ xin,
    const float* __restrict__ cw_f, const float* __restrict__ cb_f,
    const float* __restrict__ wx_f, const float* __restrict__ wdt_f, const float* __restrict__ bdt_f,
    const float* __restrict__ Al_f, const float* __restrict__ D_f,
    const float* __restrict__ cw_b, const float* __restrict__ cb_b,
    const float* __restrict__ wx_b, const float* __restrict__ wdt_b, const float* __restrict__ bdt_b,
    const float* __restrict__ Al_b, const float* __restrict__ D_b,
    float* __restrict__ yl_f, float* __restrict__ sp_f, float* __restrict__ Cc_f,
    float* __restrict__ yl_b, float* __restrict__ sp_b, float* __restrict__ Cc_b,
    float* __restrict__ aggP, float* __restrict__ aggS){
  int lane = threadIdx.x;
  int dir = blockIdx.y;
  int bb = blockIdx.z;
  int ch = blockIdx.x;
  int p0 = ch*CLEN;
  const float* cw  = dir? cw_b : cw_f;
  const float* cb  = dir? cb_b : cb_f;
  const float* wx  = dir? wx_b : wx_f;
  const float* wdt = dir? wdt_b : wdt_f;
  const float* bdt = dir? bdt_b : bdt_f;
  const float* Al  = dir? Al_b : Al_f;
  const float* Dv  = dir? D_b : D_f;
  float* ylbuf = dir? yl_b : yl_f;
  float* spbuf = dir? sp_b : sp_f;
  float* Ccb   = dir? Cc_b : Cc_f;

  __shared__ float xcs[GG*64];   // group of xc rows
  __shared__ float bcs[GG*16];   // group of Bc rows
  __shared__ float ccs[GG*16];   // group of Cc rows

  // ---- per-lane constants
  int d = lane;
  float c0=cw[d*4+0], c1=cw[d*4+1], c2=cw[d*4+2], c3=cw[d*4+3], cbv=cb[d];
  float wd0=wdt[d*2], wd1=wdt[d*2+1], bd=bdt[d];
  float Dd = Dv[d];
  float A[NS];
  #pragma unroll
  for (int n4=0;n4<4;++n4){
    float4 av = *(const float4*)&Al[d*NS + n4*4];
    A[n4*4+0] = -__expf(av.x); A[n4*4+1] = -__expf(av.y);
    A[n4*4+2] = -__expf(av.z); A[n4*4+3] = -__expf(av.w);
  }
  // x_proj: lane l owns row 2+(l&31), c-half (l>>5) -> 32 weights in regs
  int prow = 2 + (lane & 31);
  int chalf = lane >> 5;
  float wreg[32];
  #pragma unroll
  for (int i4=0;i4<8;++i4){
    float4 wv = *(const float4*)&wx[prow*64 + chalf*32 + i4*4];
    wreg[i4*4+0]=wv.x; wreg[i4*4+1]=wv.y; wreg[i4*4+2]=wv.z; wreg[i4*4+3]=wv.w;
  }
  // dt rows 0,1: lane d holds wx[0][d], wx[1][d]
  float wx0l = wx[d], wx1l = wx[64+d];
  // scan state: S (local state) + sdl (running sum of deltas)
  float S[NS];
  #pragma unroll
  for (int n=0;n<NS;++n) S[n]=0.f;
  float sdl = 0.f;
  // conv history
  float u1=0.f,u2=0.f,u3=0.f;
  #pragma unroll
  for (int k=1;k<=3;++k){
    int pos = p0 - k;
    float v = 0.f;
    if (pos >= 0){ int ls = dir? (LL-1-pos) : pos; v = xin[(bb*LL+ls)*DI + d]; }
    if(k==1) u1=v; else if(k==2) u2=v; else u3=v;
  }

  const int NG = CLEN/GG;   // 4
  for (int g=0; g<NG; ++g){
    int pbase = p0 + g*GG;
    // ---- phase A: conv1d + silu + dt-butterfly for GG tokens
    float xcr[GG], dlt[GG];
    #pragma unroll
    for (int j=0;j<GG;++j){
      int pos = pbase + j;
      int ls = dir? (LL-1-pos) : pos;
      float u0 = xin[(bb*LL+ls)*DI + d];
      float xc = siluf_(cbv + c0*u3 + c1*u2 + c2*u1 + c3*u0);
      u3=u2; u2=u1; u1=u0;
      xcr[j] = xc;
      xcs[j*64+d] = xc;
      // dt0/dt1 wave reduction (all 64 lanes)
      float pp0 = xc*wx0l, pp1 = xc*wx1l;
      #pragma unroll
      for (int i=1;i<64;i<<=1){
        pp0 += __shfl_xor(pp0, i, 64);
        pp1 += __shfl_xor(pp1, i, 64);
      }
      dlt[j] = softplusf_(pp0*wd0 + pp1*wd1 + bd);
    }
    WAVE_LDS_FENCE();
    // ---- phase B: x_proj rows 2..33, split across lane pairs
    #pragma unroll
    for (int j=0;j<GG;++j){
      float acc = 0.f;
      #pragma unroll
      for (int c4=0;c4<8;++c4){
        float4 xv = *(const float4*)&xcs[j*64 + chalf*32 + c4*4];
        acc += xv.x*wreg[c4*4+0] + xv.y*wreg[c4*4+1]
             + xv.z*wreg[c4*4+2] + xv.w*wreg[c4*4+3];
      }
      float full = acc + __shfl_xor(acc, 32, 64);
      if (lane < 32){
        if (lane < 16){
          bcs[j*16 + lane] = full;                 // Bc (LDS only)
        } else {
          int n = lane - 16;
          ccs[j*16 + n] = full;                    // Cc (LDS + global for k4)
          Ccb[(bb*LL + pbase + j)*NS + n] = full;
        }
      }
    }
    WAVE_LDS_FENCE();
    // ---- phase C: scan + y_local/sdl-prefix writes (lane = d)
    #pragma unroll
    for (int j=0;j<GG;++j){
      int tb = bb*LL + pbase + j;
      float dl = dlt[j];
      sdl += dl;                              // inclusive prefix
      spbuf[tb*DI + d] = sdl;
      float dx = dl*xcr[j];
      float yv = xcr[j]*Dd;
      #pragma unroll
      for (int n4=0;n4<4;++n4){
        float4 bv = *(const float4*)&bcs[j*16 + n4*4];   // broadcast
        float4 cv = *(const float4*)&ccs[j*16 + n4*4];   // broadcast
        float bvv[4] = {bv.x,bv.y,bv.z,bv.w};
        float cvv[4] = {cv.x,cv.y,cv.z,cv.w};
        #pragma unroll
        for (int q=0;q<4;++q){
          int n = n4*4+q;
          float dA = __expf(dl*A[n]);
          S[n] = dA*S[n] + dx*bvv[q];
          yv += S[n]*cvv[q];
        }
      }
      ylbuf[tb*DI + d] = yv;
    }
  }
  // write chunk aggregates; P[n] = exp(A[n]*sdl)
  int bdd = (bb*2+dir)*DI + d;
  float* pp = aggP + (bdd*NCH + ch)*NS;
  float* sp = aggS + (bdd*NCH + ch)*NS;
  #pragma unroll
  for (int n4=0;n4<4;++n4){
    *(float4*)&pp[n4*4] = make_float4(__expf(A[n4*4+0]*sdl),__expf(A[n4*4+1]*sdl),
                                      __expf(A[n4*4+2]*sdl),__expf(A[n4*4+3]*sdl));
    *(float4*)&sp[n4*4] = make_float4(S[n4*4+0],S[n4*4+1],S[n4*4+2],S[n4*4+3]);
  }
}

// ---------------------------------------------------------------- P2 v2: hierarchical parallel scan over chunk aggregates
// 1 block per chain-group bdd=(b,dir,d); 256 thr as (kk,n), kk owns 36 chunks.
// Sequential depth 36+16+36 (was 576). hin aliases aggP (read-before-write).
__global__ __launch_bounds__(256) void p2_scan_agg(
    const float* aggP, const float* aggS, float* hin){
  __shared__ float lP[16*17], lS[16*17];
  int tid = threadIdx.x;
  int bdd = blockIdx.x;
  int kk = tid >> 4, n = tid & 15;
  const int SEG = NCH/16;   // 36
  int base = bdd*NCH*NS;
  // phase 1: segment-local aggregate (aP,aS)
  float aP = 1.f, aS = 0.f;
  #pragma unroll 4
  for (int j=0;j<SEG;++j){
    int i = base + (kk*SEG+j)*NS + n;
    float pv = aggP[i], sv = aggS[i];
    aP *= pv;
    aS = pv*aS + sv;
  }
  lP[kk*17+n] = aP; lS[kk*17+n] = aS;
  __syncthreads();
  // phase 2: exclusive scan over the 16 segment aggregates (per n)
  if (tid < 16){
    float hent = 0.f;
    #pragma unroll
    for (int k2=0;k2<16;++k2){
      float pv = lP[k2*17+tid], sv = lS[k2*17+tid];
      lS[k2*17+tid] = hent;          // entering state for segment k2
      hent = pv*hent + sv;
    }
  }
  __syncthreads();
  // phase 3: re-walk segment, writing entering state per chunk
  float h = lS[kk*17+n];
  #pragma unroll 4
  for (int j=0;j<SEG;++j){
    int i = base + (kk*SEG+j)*NS + n;
    float pv = aggP[i], sv = aggS[i];
    hin[i] = h;
    h = pv*h + sv;
  }
}

// ---------------------------------------------------------------- K4: hin-correction + gate + out_proj + transpose -> att2
// y[t,d] = yl[t,d] + sum_n Cc[t,n]*exp(A[d,n]*sp[t,d])*hin[ch,d,n]  (both dirs)
// tile = 32 tokens = 2 chunks per dir (CLEN=16); chunk fixed per tslot.
__global__ __launch_bounds__(256) void k4_outproj(
    const float* __restrict__ yl_f, const float* __restrict__ yl_b,
    const float* __restrict__ sp_f, const float* __restrict__ sp_b,
    const float* __restrict__ Cc_f, const float* __restrict__ Cc_b,
    const float* __restrict__ Al_f, const float* __restrict__ Al_b,
    const float* __restrict__ hin, const float* __restrict__ zs,
    const float* __restrict__ w_out, float* __restrict__ att2){
  __shared__ float ccs_f[32*16], ccs_b[32*16];
  __shared__ float gt[32*64];    // [tok][d]
  __shared__ float wol[32*65];   // [c][d] padded
  __shared__ float ot[32*33];    // [c][tok] padded
  int tid = threadIdx.x;
  int tg0 = blockIdx.x*32;
  int bb = tg0/LL, l0 = tg0%LL;
  int d = tid & 63, tslot = tid >> 6;
  for (int r=0;r<8;++r){
    int idx = r*256+tid; // 2048
    wol[(idx>>6)*65 + (idx&63)] = w_out[idx];
  }
  {
    int base_f = (bb*LL + l0)*NS;
    int base_b = (bb*LL + (LL-32-l0))*NS;
    #pragma unroll
    for (int r=0;r<2;++r){
      int idx = r*256+tid;  // 512
      ccs_f[idx] = Cc_f[base_f+idx];
      ccs_b[idx] = Cc_b[base_b+idx];
    }
  }
  // per-thread A and hin; chunk is fixed per tslot (CLEN=16, 8 tokens/tslot)
  int ch_f = l0/CLEN + (tslot>>1);
  int ch_b = (LL-l0)/CLEN - 1 - (tslot>>1);
  const float* hpf = hin + (((bb*2+0)*DI + d)*NCH + ch_f)*NS;
  const float* hpb = hin + (((bb*2+1)*DI + d)*NCH + ch_b)*NS;
  float Af[NS], Ab[NS], hf[NS], hb[NS];
  #pragma unroll
  for (int n4=0;n4<4;++n4){
    float4 av = *(const float4*)&Al_f[d*NS + n4*4];
    Af[n4*4+0]=-__expf(av.x); Af[n4*4+1]=-__expf(av.y);
    Af[n4*4+2]=-__expf(av.z); Af[n4*4+3]=-__expf(av.w);
    float4 aw = *(const float4*)&Al_b[d*NS + n4*4];
    Ab[n4*4+0]=-__expf(aw.x); Ab[n4*4+1]=-__expf(aw.y);
    Ab[n4*4+2]=-__expf(aw.z); Ab[n4*4+3]=-__expf(aw.w);
    float4 hv = *(const float4*)&hpf[n4*4];
    hf[n4*4+0]=hv.x; hf[n4*4+1]=hv.y; hf[n4*4+2]=hv.z; hf[n4*4+3]=hv.w;
    float4 hw = *(const float4*)&hpb[n4*4];
    hb[n4*4+0]=hw.x; hb[n4*4+1]=hw.y; hb[n4*4+2]=hw.z; hb[n4*4+3]=hw.w;
  }
  __syncthreads();
  #pragma unroll
  for (int r=0;r<8;++r){
    int tk = tslot*8 + r;            // wave-uniform
    int l = l0 + tk;
    int tf  = (bb*LL + l)*DI + d;
    int tb2 = (bb*LL + (LL-1-l))*DI + d;
    float spf = sp_f[tf],  yf = yl_f[tf];
    float spb = sp_b[tb2], yb = yl_b[tb2];
    int jb = 31 - tk;
    float fixf = 0.f, fixb = 0.f;
    #pragma unroll
    for (int n=0;n<NS;++n){
      fixf += ccs_f[tk*16+n] * (hf[n]*__expf(Af[n]*spf));
      fixb += ccs_b[jb*16+n] * (hb[n]*__expf(Ab[n]*spb));
    }
    gt[tk*64+d] = (yf+fixf + yb+fixb) * zs[tf];
  }
  __syncthreads();
  int c = tid & 31, tsl = tid >> 5;
  for (int tg=0; tg<4; ++tg){
    int tk = tg*8+tsl;
    float acc=0.f;
    #pragma unroll
    for (int dd=0;dd<DI;++dd) acc += gt[tk*64+dd]*wol[c*65+dd];
    ot[c*33+tk] = acc;
  }
  __syncthreads();
  float* a2 = att2 + bb*CH*LL + l0;
  for (int r=0;r<4;++r){
    int idx = r*256+tid;   // 1024 = 32c x 32t
    int cc2 = idx>>5, t = idx&31;
    a2[cc2*LL + t] = ot[cc2*33+t];
  }
}

// ---------------------------------------------------------------- K5a: channel mean/max pool; 4-way c-split + LDS combine
__global__ __launch_bounds__(256) void k5a_pool(
    const float* __restrict__ x, const float* __restrict__ att2, float* __restrict__ pooled){
  __shared__ float ps[4][64], pm[4][64];
  int tid = threadIdx.x;
  int lq = tid & 63, q = tid >> 6;
  int gl = blockIdx.x*64 + lq;
  int bb = gl/LL, l = gl%LL;
  const float* xp = x + bb*CH*LL + l;
  const float* ap = att2 + bb*CH*LL + l;
  float s=0.f, m=-INFINITY;
  #pragma unroll
  for (int cc=0;cc<8;++cc){
    int c = q*8+cc;
    float v1 = xp[c*LL], v2 = ap[c*LL];
    s += v1+v2;
    m = fmaxf(m, fmaxf(v1,v2));
  }
  ps[q][lq] = s; pm[q][lq] = m;
  __syncthreads();
  if (tid < 64){
    int gl2 = blockIdx.x*64 + tid;
    int bb2 = gl2/LL, l2 = gl2%LL;
    float ss = (ps[0][tid]+ps[1][tid]) + (ps[2][tid]+ps[3][tid]);
    float mm = fmaxf(fmaxf(pm[0][tid],pm[1][tid]), fmaxf(pm[2][tid],pm[3][tid]));
    pooled[(bb2*2+0)*LL + l2] = ss*(1.f/64.f);
    pooled[(bb2*2+1)*LL + l2] = mm;
  }
}

// ---------------------------------------------------------------- K5b: 7x7 SE conv + sigmoid + combine; 4-way (o,i)-split
__global__ __launch_bounds__(256) void k5b_se_combine(
    const float* __restrict__ x, const float* __restrict__ att2,
    const float* __restrict__ pooled, const float* __restrict__ w_se,
    const float* __restrict__ b_se, float* __restrict__ outbuf){
  __shared__ float pb[4][64];
  __shared__ float sep[2][64];
  int tid = threadIdx.x;
  int lq = tid & 63, q = tid >> 6;
  int i = q & 1, o = q >> 1;
  int gl = blockIdx.x*64 + lq;
  int bb = gl/LL, l = gl%LL;
  int h0 = l/WW, w0 = l%WW;
  const float* pp = pooled + (bb*2+i)*LL;
  const float* wp = w_se + (o*2+i)*49;
  float a = 0.f;
  #pragma unroll
  for (int kh=0;kh<7;++kh){
    int hh = h0+kh-3; if((unsigned)hh>=HH) continue;
    const float* row = pp + hh*WW;
    #pragma unroll
    for (int kw=0;kw<7;++kw){
      int ww2 = w0+kw-3;
      if((unsigned)ww2<WW) a += row[ww2]*wp[kh*7+kw];
    }
  }
  pb[q][lq] = a;
  __syncthreads();
  if (tid < 128){
    int oo = tid >> 6, l2 = tid & 63;
    sep[oo][l2] = sigmoidf_(b_se[oo] + pb[oo*2+0][l2] + pb[oo*2+1][l2]);
  }
  __syncthreads();
  float se0 = sep[0][lq], se1 = sep[1][lq];
  const float* xp = x + bb*CH*LL + l;
  const float* ap = att2 + bb*CH*LL + l;
  float* op = outbuf + bb*CH*LL + l;
  #pragma unroll
  for (int cc=0;cc<8;++cc){
    int c = q*8+cc;
    op[c*LL] = xp[c*LL]*se0 + ap[c*LL]*se1;
  }
}

// ---------------------------------------------------------------- K6: 3x3 conv 32->64 (pad=1), LDS row-banded, co-split
__global__ __launch_bounds__(256) void k6_conv3x3(
    const float* __restrict__ inb, const float* __restrict__ wc,
    const float* __restrict__ bc, float* __restrict__ out){
  __shared__ float lds[CH*3*98];
  int tid = threadIdx.x;
  int h = blockIdx.x, cohalf = blockIdx.y, bb = blockIdx.z;
  const float* ib = inb + bb*CH*LL;
  for (int r=0; r<36; ++r){           // 36*256 = 9216 = 32ci*3rows*96w
    int idx = r*256+tid;
    int ci = idx/(3*96); int rr = (idx/96)%3; int ww2 = idx%96;
    int hh = h + rr - 1;
    float v = ((unsigned)hh < HH) ? ib[ci*LL + hh*WW + ww2] : 0.f;
    lds[(ci*3+rr)*98 + 1 + ww2] = v;
  }
  if (tid < 96){
    int ci = tid/3, rr = tid%3;
    lds[(ci*3+rr)*98 + 0]  = 0.f;
    lds[(ci*3+rr)*98 + 97] = 0.f;
  }
  __syncthreads();
  int coslot = tid >> 4, wslot = tid & 15;
  int co0 = cohalf*32 + coslot*2, wb = wslot*6;
  float acc[2][6];
  #pragma unroll
  for (int q=0;q<2;++q)
    #pragma unroll
    for (int j2=0;j2<6;++j2) acc[q][j2]=0.f;
  for (int ci=0; ci<CH; ++ci){
    float wt[2][9];
    #pragma unroll
    for (int q=0;q<2;++q){
      const float* wp = wc + ((co0+q)*CH + ci)*9;
      #pragma unroll
      for (int k=0;k<9;++k) wt[q][k] = wp[k];
    }
    #pragma unroll
    for (int kh=0;kh<3;++kh){
      const float* row = &lds[(ci*3+kh)*98 + wb];
      float s[8];
      #pragma unroll
      for (int t2=0;t2<8;++t2) s[t2] = row[t2];
      #pragma unroll
      for (int q=0;q<2;++q)
        #pragma unroll
        for (int kw=0;kw<3;++kw){
          float wv = wt[q][kh*3+kw];
          #pragma unroll
          for (int j2=0;j2<6;++j2) acc[q][j2] += s[j2+kw]*wv;
        }
    }
  }
  #pragma unroll
  for (int q=0;q<2;++q){
    int co = co0+q;
    float bv = bc[co];
    float* op = out + (bb*64 + co)*LL + h*WW + wb;
    #pragma unroll
    for (int j2=0;j2<6;++j2) op[j2] = acc[q][j2]+bv;
  }
}

// ---------------------------------------------------------------- launch
extern "C" void kernel_launch(void* const* d_in, const int* in_sizes, int n_in,
                              void* d_out, int out_size, void* d_ws, size_t ws_size,
                              hipStream_t stream){
  const float* x     = (const float*)d_in[0];
  const float* w_att = (const float*)d_in[1];
  const float* b_att = (const float*)d_in[2];
  const float* ln_w  = (const float*)d_in[3];
  const float* ln_b  = (const float*)d_in[4];
  const float* w_in  = (const float*)d_in[5];
  const float* cw_f  = (const float*)d_in[6];
  const float* cb_f  = (const float*)d_in[7];
  const float* wx_f  = (const float*)d_in[8];
  const float* wdt_f = (const float*)d_in[9];
  const float* bdt_f = (const float*)d_in[10];
  const float* Al_f  = (const float*)d_in[11];
  const float* D_f   = (const float*)d_in[12];
  const float* cw_b  = (const float*)d_in[13];
  const float* cb_b  = (const float*)d_in[14];
  const float* wx_b  = (const float*)d_in[15];
  const float* wdt_b = (const float*)d_in[16];
  const float* bdt_b = (const float*)d_in[17];
  const float* Al_b  = (const float*)d_in[18];
  const float* D_b   = (const float*)d_in[19];
  const float* w_out = (const float*)d_in[20];
  const float* w_se  = (const float*)d_in[21];
  const float* b_se  = (const float*)d_in[22];
  const float* w_conv= (const float*)d_in[23];
  const float* b_conv= (const float*)d_in[24];

  float* ws = (float*)d_ws;
  // region aliasing (stream-ordered):
  //   xa (dead after K2)  <- att2 (written K4)
  //   xin (dead after K3) <- outbuf (written K5b)
  //   hin = aggP in-place (P2 reads agg[i] before writing hin[i])
  float* xa     = ws + 0;          // 1179648
  float* att2   = ws + 0;
  float* xin    = ws + 1179648;    // 2359296
  float* outbuf = ws + 1179648;
  float* zs     = ws + 3538944;    // 2359296
  float* yl_f   = ws + 5898240;    // 2359296
  float* yl_b   = ws + 8257536;    // 2359296
  float* sp_f   = ws + 10616832;   // 2359296
  float* sp_b   = ws + 12976128;   // 2359296
  float* Cc_f   = ws + 15335424;   // 589824
  float* Cc_b   = ws + 15925248;   // 589824
  float* aggP   = ws + 16515072;   // 4718592 (NCH=576)
  float* aggS   = ws + 21233664;   // 4718592
  float* hin    = aggP;            // in-place
  float* pooled = ws + 25952256;   // 73728
  // total 26025984 floats = 99.3 MiB

  k1_conv_att<<<4608,256,0,stream>>>(x, w_att, b_att, xa);
  k2_ln_inproj<<<1152,128,0,stream>>>(xa, w_in, ln_w, ln_b, xin, zs);
  k3_fused<<<dim3(NCH,2,BB),64,0,stream>>>(xin,
      cw_f,cb_f,wx_f,wdt_f,bdt_f,Al_f,D_f,
      cw_b,cb_b,wx_b,wdt_b,bdt_b,Al_b,D_b,
      yl_f,sp_f,Cc_f, yl_b,sp_b,Cc_b, aggP,aggS);
  p2_scan_agg<<<BB*2*DI,256,0,stream>>>(aggP,aggS,hin);
  k4_outproj<<<1152,256,0,stream>>>(yl_f,yl_b, sp_f,sp_b, Cc_f,Cc_b,
      Al_f,Al_b, hin, zs, w_out, att2);
  k5a_pool<<<576,256,0,stream>>>(x, att2, pooled);
  k5b_se_combine<<<576,256,0,stream>>>(x, att2, pooled, w_se, b_se, outbuf);
  k6_conv3x3<<<dim3(HH,2,BB),256,0,stream>>>(outbuf, w_conv, b_conv, (float*)d_out);
}